// Round 10
// baseline (169.302 us; speedup 1.0000x reference)
//
#include <hip/hip_runtime.h>
#include <stdint.h>

#define NS 65536      // B*H*W samples
#define D 64          // embed dim
#define K 1024        // codebook size
#define NEL 4194304   // NS*D
#define MARGIN_KEY 0.025f  // key units (= half dist units); covers bf16 approx err ~3e-3

typedef short bf16x8 __attribute__((ext_vector_type(8)));
typedef float f32x4 __attribute__((ext_vector_type(4)));
typedef float f32x16 __attribute__((ext_vector_type(16)));

static __device__ __forceinline__ unsigned short bf16_rne(float x) {
    union { float f; uint32_t u; } v; v.f = x;
    uint32_t r = v.u + 0x7FFFu + ((v.u >> 16) & 1u);
    return (unsigned short)(r >> 16);
}
static __device__ __forceinline__ float bf16f(unsigned short h) {
    union { uint32_t u; float f; } v; v.u = ((uint32_t)h) << 16;
    return v.f;
}

// ---------------------------------------------------------------------------
// Prep (validated r8/r9): codebook -> bf16 hi/lo per 32-code tile in
// MFMA-fragment order P[t][f][lane][8]; cn-augmentation frags P2[t][lane][8]
// from exact fp32 cnorm; ||m||^2; zero acc + counter.
// ---------------------------------------------------------------------------
__global__ __launch_bounds__(256) void vq_prep(
    const float* __restrict__ cm,        // [D,K]
    unsigned short* __restrict__ P,      // packed frags, 256 KB
    unsigned short* __restrict__ P2,     // cn frags, 32 KB
    float* __restrict__ cnorm,           // [K]
    double* __restrict__ acc,
    unsigned int* __restrict__ cnt)
{
    const int tx = threadIdx.x;
    const int c  = tx & 31;              // code within tile
    const int dg = tx >> 5;              // dim group 0..7 (8 dims each)
    const int t  = blockIdx.x;           // tile 0..31
    const int k  = t * 32 + c;
    if (t == 0 && tx == 0) { *acc = 0.0; *cnt = 0u; }

    float p = 0.f;
    bf16x8 hv, lv;
#pragma unroll
    for (int j = 0; j < 8; ++j) {
        float v = cm[(dg * 8 + j) * K + k];   // coalesced over c
        unsigned short hb = bf16_rne(v);
        hv[j] = (short)hb;
        lv[j] = (short)bf16_rne(v - bf16f(hb));
        p = fmaf(v, v, p);
    }
    const int s = dg >> 1, kh = dg & 1;
    *(bf16x8*)(P + ((size_t)(t * 8 + s) * 64 + kh * 32 + c) * 8)     = hv;
    *(bf16x8*)(P + ((size_t)(t * 8 + 4 + s) * 64 + kh * 32 + c) * 8) = lv;

    __shared__ float pn[32][9];
    pn[c][dg] = p;
    __syncthreads();
    if (tx < 32) {
        float sm = 0.f;
#pragma unroll
        for (int g = 0; g < 8; ++g) sm += pn[tx][g];
        cnorm[t * 32 + tx] = sm;
        unsigned short chi = bf16_rne(-0.5f * sm);
        unsigned short clo = bf16_rne(-0.5f * sm - bf16f(chi));
        bf16x8 a;
#pragma unroll
        for (int j = 0; j < 8; ++j) a[j] = 0;
        a[0] = (short)chi; a[1] = (short)clo;
        *(bf16x8*)(P2 + (size_t)t * 512 + tx * 8) = a;
    } else if (tx < 64) {
        bf16x8 a;
#pragma unroll
        for (int j = 0; j < 8; ++j) a[j] = 0;
        *(bf16x8*)(P2 + (size_t)t * 512 + tx * 8) = a;
    }
}

// ---------------------------------------------------------------------------
// Main: CODES-STATIONARY (r8/r9 kernel, correctness-validated twice).
// r8 (__launch_bounds__(512,2)) and r9 ((512,1)) both produced VGPR_Count =
// 128 + 157 MB of scratch-spill FETCH: launch_bounds' 2nd arg is a waves/EU
// MINIMUM only -- the backend heuristic still targeted 4 waves/EU and
// budgeted 512/4 = 128 VGPRs, spilling the 128-VGPR register codebook.
// FIX: __attribute__((amdgpu_waves_per_eu(1, 2))) -- sets min AND MAX;
// max=2 forces the register budget to >= 512/2 = 256 VGPRs (unified file,
// accum_offset split covers ~220 arch + ~32 acc live). LDS 89 KB -> 1
// block/CU -> 2 waves/SIMD, consistent with the forced range.
// Structure: 256 blocks (1/CU) x 512 thr (8 waves); wave w holds codes
// w*128..+128 (4 tiles x 4 slices x hi/lo = 128 VGPR, loaded once).
// Samples stream through LDS in 8 tiles of 32 (double-buffered, 1
// barrier/tile). Per tile/wave: 8 ds_read_b128 sample frags shared by 4
// code-tile chains (2-way ILP), 52 MFMAs. cn rides as an extra MFMA
// K-slice (A4 x B4={1,1}) -> acc = dot - cn/2 (track MAX). Explicit-index
// top-2. mfma(codes, samples): C col = sample, row (code) =
// (r&3)+8*(r>>2)+4*(lane>>5). Margin cases rescored exactly in fp32.
// Finalize fused via completion counter (validated).
// ---------------------------------------------------------------------------
__global__ __launch_bounds__(512)
__attribute__((amdgpu_waves_per_eu(1, 2)))
void vq_main(
    const float* __restrict__ xin,           // [NS,D]
    const float* __restrict__ cm,            // [D,K] (exact rescore)
    const unsigned short* __restrict__ P,    // packed code frags
    const unsigned short* __restrict__ P2,   // cn frags
    const float* __restrict__ cnorm,         // [K]
    float* __restrict__ outq,                // [NS,D]
    float* __restrict__ outidx,              // [NS]
    double* __restrict__ acc_g,
    unsigned int* __restrict__ cnt_g,
    float* __restrict__ loss_out)
{
    __shared__ unsigned short xb[8192];      // [buf][src][slice][512] 16 KB
    __shared__ float pt1[256 * 17];          // per-sample key partials
    __shared__ float pt2[256 * 17];
    __shared__ int   pi1[256 * 17];          // per-sample index partials
    __shared__ int   pi2[256 * 17];
    __shared__ int   widx[256];
    __shared__ float red[512];

    const int tx = threadIdx.x;
    const int S0 = blockIdx.x * 256;
    const int w = tx >> 6, l = tx & 63;

    // ---- load this wave's 128 codes + cn frags into registers (once) ----
    bf16x8 CH[4][4], CL[4][4], A4[4];        // [code-tile][slice]
#pragma unroll
    for (int t = 0; t < 4; ++t) {
#pragma unroll
        for (int s = 0; s < 4; ++s) {
            CH[t][s] = *(const bf16x8*)(P + ((size_t)((w * 4 + t) * 8 + s) * 64 + l) * 8);
            CL[t][s] = *(const bf16x8*)(P + ((size_t)((w * 4 + t) * 8 + 4 + s) * 64 + l) * 8);
        }
        A4[t] = *(const bf16x8*)(P2 + (size_t)(w * 4 + t) * 512 + l * 8);
    }
    bf16x8 B4;
#pragma unroll
    for (int j = 0; j < 8; ++j) B4[j] = 0;
    if (l < 32) { B4[0] = (short)0x3F80; B4[1] = (short)0x3F80; }   // 1.0 bf16

    // ---- stage sample tile 0 (threads 0-255 own frag (slice, lane)) ----
    if (tx < 256) {
        const int ss = tx >> 6, sll = tx & 63;
        const int skh = sll >> 5, ssp = sll & 31;
        const float* gp = xin + (size_t)(S0 + ssp) * D + ss * 16 + skh * 8;
        bf16x8 h8, l8;
#pragma unroll
        for (int j = 0; j < 8; ++j) {
            float v = gp[j];
            unsigned short hb = bf16_rne(v);
            h8[j] = (short)hb;
            l8[j] = (short)bf16_rne(v - bf16f(hb));
        }
        *(bf16x8*)(xb + (0 * 4 + ss) * 512 + sll * 8) = h8;   // buf0 hi
        *(bf16x8*)(xb + (1 * 4 + ss) * 512 + sll * 8) = l8;   // buf0 lo
    }

    const f32x16 Z16 = {0.f,0.f,0.f,0.f,0.f,0.f,0.f,0.f,
                        0.f,0.f,0.f,0.f,0.f,0.f,0.f,0.f};
    const int ibase = w * 128 + 4 * (l >> 5);   // + T*32 + rowoff(r) = code

    __syncthreads();   // tile 0 staged

#define MFMA32(A, B, C) __builtin_amdgcn_mfma_f32_32x32x16_bf16(A, B, C, 0, 0, 0)
#define PAIR(T0, T1) do {                                                      \
        f32x16 a0_ = MFMA32(A4[T0], B4, Z16);                                  \
        f32x16 a1_ = MFMA32(A4[T1], B4, Z16);                                  \
        _Pragma("unroll")                                                      \
        for (int s = 0; s < 4; ++s) {                                          \
            a0_ = MFMA32(CH[T0][s], Bh[s], a0_);                               \
            a1_ = MFMA32(CH[T1][s], Bh[s], a1_);                               \
        }                                                                      \
        _Pragma("unroll")                                                      \
        for (int s = 0; s < 4; ++s) {                                          \
            a0_ = MFMA32(CL[T0][s], Bh[s], a0_);                               \
            a1_ = MFMA32(CL[T1][s], Bh[s], a1_);                               \
        }                                                                      \
        _Pragma("unroll")                                                      \
        for (int s = 0; s < 4; ++s) {                                          \
            a0_ = MFMA32(CH[T0][s], Bl[s], a0_);                               \
            a1_ = MFMA32(CH[T1][s], Bl[s], a1_);                               \
        }                                                                      \
        _Pragma("unroll")                                                      \
        for (int r = 0; r < 16; ++r) {                                         \
            const int ro_ = (r & 3) + 8 * (r >> 2);                            \
            float v0_ = a0_[r];                                                \
            const int ix0_ = ibase + (T0) * 32 + ro_;                          \
            bool c1_ = v0_ > b1, c2_ = v0_ > b2;                               \
            b2 = __builtin_amdgcn_fmed3f(b1, v0_, b2);                         \
            b1 = fmaxf(b1, v0_);                                               \
            i2 = c1_ ? i1 : (c2_ ? ix0_ : i2);                                 \
            i1 = c1_ ? ix0_ : i1;                                              \
            float v1_ = a1_[r];                                                \
            const int ix1_ = ibase + (T1) * 32 + ro_;                          \
            bool d1_ = v1_ > b1, d2_ = v1_ > b2;                               \
            b2 = __builtin_amdgcn_fmed3f(b1, v1_, b2);                         \
            b1 = fmaxf(b1, v1_);                                               \
            i2 = d1_ ? i1 : (d2_ ? ix1_ : i2);                                 \
            i1 = d1_ ? ix1_ : i1;                                              \
        }                                                                      \
    } while (0)

    for (int st = 0; st < 8; ++st) {
        const int b = st & 1;
        // sample frags for tile st (shared by all 4 code-tiles)
        bf16x8 Bh[4], Bl[4];
#pragma unroll
        for (int s = 0; s < 4; ++s) {
            Bh[s] = *(const bf16x8*)(xb + ((b * 2 + 0) * 4 + s) * 512 + l * 8);
            Bl[s] = *(const bf16x8*)(xb + ((b * 2 + 1) * 4 + s) * 512 + l * 8);
        }
        // prefetch next tile's fp32 (hides HBM under the MFMA block)
        float4 xv0, xv1;
        const int ss = tx >> 6, sll = tx & 63;
        const int skh = sll >> 5, ssp = sll & 31;
        if (tx < 256 && st < 7) {
            const float* gp = xin + (size_t)(S0 + (st + 1) * 32 + ssp) * D
                              + ss * 16 + skh * 8;
            xv0 = *(const float4*)(gp);
            xv1 = *(const float4*)(gp + 4);
        }

        float b1 = -3.4e38f, b2 = -3.4e38f;   // MAX of key = dot - cn/2
        int i1 = 0, i2 = 0;
        PAIR(0, 1);
        PAIR(2, 3);

        // per-lane partial (stride 17: 32 lanes x stride-17 = conflict-free)
        const int si = st * 32 + (l & 31);
        const int sp = w * 2 + (l >> 5);
        pt1[si * 17 + sp] = b1;  pi1[si * 17 + sp] = i1;
        pt2[si * 17 + sp] = b2;  pi2[si * 17 + sp] = i2;

        // stage next tile into the other buffer
        if (tx < 256 && st < 7) {
            bf16x8 h8, l8;
            float vv[8] = {xv0.x, xv0.y, xv0.z, xv0.w, xv1.x, xv1.y, xv1.z, xv1.w};
#pragma unroll
            for (int j = 0; j < 8; ++j) {
                unsigned short hb = bf16_rne(vv[j]);
                h8[j] = (short)hb;
                l8[j] = (short)bf16_rne(vv[j] - bf16f(hb));
            }
            const int nb = b ^ 1;
            *(bf16x8*)(xb + ((nb * 2 + 0) * 4 + ss) * 512 + sll * 8) = h8;
            *(bf16x8*)(xb + ((nb * 2 + 1) * 4 + ss) * 512 + sll * 8) = l8;
        }
        __syncthreads();
    }

    // ---- merge 16 partials per sample; margin-rescore; pick winner ----
    if (tx < 256) {
        float B1 = -3.4e38f, B2 = -3.4e38f; int I1 = 0, I2 = 0;
#pragma unroll
        for (int p = 0; p < 16; ++p) {
            float v1 = pt1[tx * 17 + p];  int j1 = pi1[tx * 17 + p];
            float v2 = pt2[tx * 17 + p];  int j2 = pi2[tx * 17 + p];
            if (v1 > B1)      { B2 = B1; I2 = I1; B1 = v1; I1 = j1; }
            else if (v1 > B2) { B2 = v1; I2 = j1; }
            if (v2 > B1)      { B2 = B1; I2 = I1; B1 = v2; I1 = j2; }
            else if (v2 > B2) { B2 = v2; I2 = j2; }
        }
        int winner = I1;
        if (B1 - B2 < MARGIN_KEY) {
            // exact fp32 rescore (key = dot - cn/2; larger = closer)
            const float* xp = xin + (size_t)(S0 + tx) * D;
            float a0 = 0, a1 = 0, a2 = 0, a3 = 0, e0 = 0, e1 = 0, e2 = 0, e3 = 0;
            for (int dd = 0; dd < D; dd += 4) {
                float x0 = xp[dd], x1 = xp[dd + 1], x2 = xp[dd + 2], x3 = xp[dd + 3];
                a0 = fmaf(x0, cm[(dd + 0) * K + I1], a0);
                a1 = fmaf(x1, cm[(dd + 1) * K + I1], a1);
                a2 = fmaf(x2, cm[(dd + 2) * K + I1], a2);
                a3 = fmaf(x3, cm[(dd + 3) * K + I1], a3);
                e0 = fmaf(x0, cm[(dd + 0) * K + I2], e0);
                e1 = fmaf(x1, cm[(dd + 1) * K + I2], e1);
                e2 = fmaf(x2, cm[(dd + 2) * K + I2], e2);
                e3 = fmaf(x3, cm[(dd + 3) * K + I2], e3);
            }
            float k1 = ((a0 + a1) + (a2 + a3)) - 0.5f * cnorm[I1];
            float k2 = ((e0 + e1) + (e2 + e3)) - 0.5f * cnorm[I2];
            if (k2 > k1 || (k2 == k1 && I2 < I1)) winner = I2;
        }
        widx[tx] = winner;
    }
    __syncthreads();

    // ---- gather (hi+lo reconstruct from P) + STE + loss partial ----
    float psum = 0.f;
    {
        const int sl = tx >> 1;
        const int wi = widx[sl];
        const int gt = wi >> 5, row = wi & 31;
        const int gs = S0 + sl;
#pragma unroll
        for (int g2 = 0; g2 < 2; ++g2) {
            const int d0 = (tx & 1) * 32 + g2 * 16;
            const int s4 = d0 >> 4;
            const unsigned short* gh = P + ((size_t)(gt * 8 + s4) * 64 + row) * 8;
            const unsigned short* gl = P + ((size_t)(gt * 8 + 4 + s4) * 64 + row) * 8;
            bf16x8 h0 = *(const bf16x8*)(gh);          // dims d0..+8 (kh=0)
            bf16x8 h1 = *(const bf16x8*)(gh + 256);    // dims d0+8..+16 (kh=1)
            bf16x8 l0 = *(const bf16x8*)(gl);
            bf16x8 l1 = *(const bf16x8*)(gl + 256);
            const float* xr = xin + (size_t)gs * D + d0;
            float* oq = outq + (size_t)gs * D + d0;
#pragma unroll
            for (int g = 0; g < 4; ++g) {
                float4 xv = *(const float4*)(xr + 4 * g);
                float q0 = bf16f((unsigned short)(g < 2 ? h0[4*g+0] : h1[4*g-8+0])) +
                           bf16f((unsigned short)(g < 2 ? l0[4*g+0] : l1[4*g-8+0]));
                float q1 = bf16f((unsigned short)(g < 2 ? h0[4*g+1] : h1[4*g-8+1])) +
                           bf16f((unsigned short)(g < 2 ? l0[4*g+1] : l1[4*g-8+1]));
                float q2 = bf16f((unsigned short)(g < 2 ? h0[4*g+2] : h1[4*g-8+2])) +
                           bf16f((unsigned short)(g < 2 ? l0[4*g+2] : l1[4*g-8+2]));
                float q3 = bf16f((unsigned short)(g < 2 ? h0[4*g+3] : h1[4*g-8+3])) +
                           bf16f((unsigned short)(g < 2 ? l0[4*g+3] : l1[4*g-8+3]));
                float dx = q0 - xv.x, dy = q1 - xv.y, dz = q2 - xv.z, dw = q3 - xv.w;
                float4 o;
                o.x = xv.x + dx; o.y = xv.y + dy; o.z = xv.z + dz; o.w = xv.w + dw;
                *(float4*)(oq + 4 * g) = o;
                psum = fmaf(dx, dx, psum);
                psum = fmaf(dy, dy, psum);
                psum = fmaf(dz, dz, psum);
                psum = fmaf(dw, dw, psum);
            }
        }
    }

    if (tx < 256)
        outidx[S0 + tx] = (float)widx[tx];

    red[tx] = psum;
    __syncthreads();
    for (int st2 = 256; st2 > 0; st2 >>= 1) {
        if (tx < st2) red[tx] += red[tx + st2];
        __syncthreads();
    }
    if (tx == 0) {
        atomicAdd(acc_g, (double)red[0]);
        __threadfence();
        unsigned prev = atomicAdd(cnt_g, 1u);
        if (prev == gridDim.x - 1) {          // last block: fused finalize
            __threadfence();
            double a = atomicAdd(acc_g, 0.0); // device-scope read of total
            float m = (float)(a / (double)NEL);
            *loss_out = m + 0.25f * m;
        }
    }
#undef PAIR
#undef MFMA32
}

extern "C" void kernel_launch(void* const* d_in, const int* in_sizes, int n_in,
                              void* d_out, int out_size, void* d_ws, size_t ws_size,
                              hipStream_t stream) {
    const float* xin = (const float*)d_in[0];   // [16,64,64,64] fp32
    const float* cm  = (const float*)d_in[1];   // [64,1024] fp32

    float* out     = (float*)d_out;
    float* outq    = out;                 // 4194304 floats
    float* outidx  = out + NEL;           // 65536 floats (indices)
    float* outloss = out + NEL + NS;      // 1 float

    // workspace: P 256 KB | cnorm 4 KB | P2 32 KB | acc 8 B | cnt 4 B
    unsigned short* P  = (unsigned short*)d_ws;
    float*  cnorm = (float*)((char*)d_ws + 262144);
    unsigned short* P2 = (unsigned short*)((char*)d_ws + 266240);
    double* acc   = (double*)((char*)d_ws + 299008);
    unsigned int* cnt = (unsigned int*)((char*)d_ws + 299016);

    vq_prep<<<32, 256, 0, stream>>>(cm, P, P2, cnorm, acc, cnt);
    vq_main<<<256, 512, 0, stream>>>(xin, cm, P, P2, cnorm, outq, outidx,
                                     acc, cnt, outloss);
}

// Round 11
// 155.999 us; speedup vs baseline: 1.0853x; 1.0853x over previous
//
#include <hip/hip_runtime.h>
#include <stdint.h>

#define NS 65536      // B*H*W samples
#define D 64          // embed dim
#define K 1024        // codebook size
#define NEL 4194304   // NS*D
#define MARGIN_KEY 0.025f  // key units (= half dist units); approx+pack err ~2e-3

typedef short bf16x8 __attribute__((ext_vector_type(8)));
typedef short s16x4 __attribute__((ext_vector_type(4)));
typedef float f32x4 __attribute__((ext_vector_type(4)));

static __device__ __forceinline__ unsigned short bf16_rne(float x) {
    union { float f; uint32_t u; } v; v.f = x;
    uint32_t r = v.u + 0x7FFFu + ((v.u >> 16) & 1u);
    return (unsigned short)(r >> 16);
}
static __device__ __forceinline__ float bf16f(unsigned short h) {
    union { uint32_t u; float f; } v; v.u = ((uint32_t)h) << 16;
    return v.f;
}

// ---------------------------------------------------------------------------
// Prep (round-5 validated): split codebook into bf16 hi/lo, packed per
// 16-code tile in MFMA-fragment order:
//   P[t][f: 0=hi d0-31, 1=hi d32-63, 2=lo d0-31, 3=lo d32-63][lane][8]
//   lane = ((d&31)>>3)*16 + (k&15).  Per tile = 4 KB contiguous.
// Also ||m_k||^2 fp32 + zero loss acc + completion counter.
// ---------------------------------------------------------------------------
__global__ __launch_bounds__(256) void vq_prep(
    const float* __restrict__ cm,        // [D,K]
    unsigned short* __restrict__ P,      // packed frags, 256 KB
    float* __restrict__ cnorm,           // [K]
    double* __restrict__ acc,
    unsigned int* __restrict__ cnt)
{
    const int tx = threadIdx.x;
    const int col = tx & 15;             // code within block's 16
    const int dg = tx >> 4;              // dim group 0..15 (4 dims each)
    const int b = blockIdx.x;            // == tile index t
    const int k = b * 16 + col;
    if (b == 0 && tx == 0) { *acc = 0.0; *cnt = 0u; }

    float p = 0.f;
    s16x4 hv, lv;
#pragma unroll
    for (int j = 0; j < 4; ++j) {
        float v = cm[(dg * 4 + j) * K + k];   // 16 consecutive floats / 16 lanes
        unsigned short hb = bf16_rne(v);
        hv[j] = (short)hb;
        lv[j] = (short)bf16_rne(v - bf16f(hb));
        p = fmaf(v, v, p);
    }
    const int lane = ((dg >> 1) & 3) * 16 + col;
    const int e0 = (dg & 1) * 4;
    unsigned short* ph = P + ((size_t)(b * 4 + (dg >> 3)) * 64 + lane) * 8 + e0;
    unsigned short* pl = P + ((size_t)(b * 4 + 2 + (dg >> 3)) * 64 + lane) * 8 + e0;
    *(s16x4*)ph = hv;
    *(s16x4*)pl = lv;

    __shared__ float pn[16][17];
    pn[col][dg] = p;
    __syncthreads();
    if (tx < 16) {
        float s = 0.f;
#pragma unroll
        for (int g = 0; g < 16; ++g) s += pn[tx][g];
        cnorm[b * 16 + tx] = s;
    }
}

// ---------------------------------------------------------------------------
// Main (round-5 kernel verbatim -- the session's best verified config:
// main 57.4us, VGPR 52, zero spill) + fused finalize (validated r6/r8-r10).
// 1024 blocks x 256 thr (4 waves), 64 samples/block (16/wave). LDS 39.1 KB
// -> 4 independent blocks/CU. B tiles (4 KB) staged into a 4-deep LDS ring
// via global_load_lds, prefetch distance 3. Per tile: vmcnt(2) -> own share
// landed; raw s_barrier -> all waves' shares landed (never vmcnt(0)
// in-loop); issue t+3 into buf[(t-1)&3] (consumed-before-barrier, safe);
// 4x ds_read_b128 + 6 MFMA (3+3 chains) + packed-index top-2 (tile idx in
// low 6 mantissa bits, err << margin). x staged NEGATED: key = ||m||^2/2 -
// x.m directly from MFMA C-in. Margin cases rescored exactly in fp32.
// Session note: the 57us main is a per-iteration latency floor -- it
// survived barrier-free streaming (r2), lockstep ring (r4), independent
// ring (r5), 32x32 tiles (r6); codes-stationary (r7-r10) is blocked by the
// allocator capping 512-thr workgroups at 128 VGPR (spills the codebook).
// ---------------------------------------------------------------------------
__global__ __launch_bounds__(256, 4) void vq_main(
    const float* __restrict__ xin,           // [NS,D]
    const float* __restrict__ cm,            // [D,K] (exact rescore)
    const unsigned short* __restrict__ P,    // packed frags
    const float* __restrict__ cnorm,         // [K]
    float* __restrict__ outq,                // [NS,D]
    float* __restrict__ outidx,              // [NS]
    double* __restrict__ acc_g,
    unsigned int* __restrict__ cnt_g,
    float* __restrict__ loss_out)
{
    // smemA phase1: xh[64][72] + xl[64][72] (18432 B), -x bf16 hi/lo
    // smemA phase2 (alias): skewed packed mb1/mb2 (2 x 4352 B)
    // smemA phase3 (alias): red f32[256]
    __shared__ char smemA[18432];
    __shared__ unsigned short btile[4][2048];   // 4-deep ring of 4 KB B tiles
    __shared__ float cn_lds[1024];              // ||m||^2 / 2
    __shared__ int   widx[64];

    unsigned short* xh = (unsigned short*)smemA;            // stride 72
    unsigned short* xl = (unsigned short*)(smemA + 9216);
    float* mb1 = (float*)smemA;
    float* mb2 = (float*)(smemA + 4352);
    float* red = (float*)smemA;

    const int tx = threadIdx.x;
    const int S0 = blockIdx.x * 64;
    const int w = tx >> 6, l = tx & 63;
    const int quad = l >> 4, col = l & 15;

#define ISSUE(T) do {                                                          \
        const unsigned short* g_ = P + (size_t)(T) * 2048 + tx * 8;            \
        __builtin_amdgcn_global_load_lds(g_, &btile[(T) & 3][tx * 8], 16, 0, 0); \
    } while (0)
#define WAITV(N) asm volatile("s_waitcnt vmcnt(" #N ")" ::: "memory")

    // prologue: stage tiles 0..2 (drained by the staging __syncthreads)
    ISSUE(0); ISSUE(1); ISSUE(2);

    // ---- stage -x -> bf16 hi/lo in LDS (one-time) ----
    {
        const int s = tx >> 2, d0 = (tx & 3) * 16;
        const float* gp = xin + (size_t)(S0 + s) * D + d0;
        bf16x8 hv0, hv1, lv0, lv1;
#pragma unroll
        for (int j = 0; j < 8; ++j) {
            float va = -gp[j], vb = -gp[8 + j];
            unsigned short ha = bf16_rne(va), hb = bf16_rne(vb);
            hv0[j] = (short)ha; hv1[j] = (short)hb;
            lv0[j] = (short)bf16_rne(va - bf16f(ha));
            lv1[j] = (short)bf16_rne(vb - bf16f(hb));
        }
        *(bf16x8*)(xh + s * 72 + d0)     = hv0;
        *(bf16x8*)(xh + s * 72 + d0 + 8) = hv1;
        *(bf16x8*)(xl + s * 72 + d0)     = lv0;
        *(bf16x8*)(xl + s * 72 + d0 + 8) = lv1;
#pragma unroll
        for (int q = 0; q < 4; ++q)
            cn_lds[q * 256 + tx] = 0.5f * cnorm[q * 256 + tx];
    }
    __syncthreads();   // drains x writes AND tiles 0-2 (full drain, once)

    // loop-invariant A fragments (-x): row = w*16 + col, dims quad*8 (+32)
    const int srow = w * 16 + col;
    bf16x8 AH0 = *(const bf16x8*)(xh + srow * 72 + quad * 8);
    bf16x8 AH1 = *(const bf16x8*)(xh + srow * 72 + 32 + quad * 8);
    bf16x8 AL0 = *(const bf16x8*)(xl + srow * 72 + quad * 8);
    bf16x8 AL1 = *(const bf16x8*)(xl + srow * 72 + 32 + quad * 8);

    // top-2 of key = cn/2 - x.m, tile idx packed in low 6 mantissa bits
    float b1[4], b2[4];
#pragma unroll
    for (int r = 0; r < 4; ++r) { b1[r] = 3.4e38f; b2[r] = 3.4e38f; }

#define BODY(T) do {                                                           \
        const unsigned short* bt_ = &btile[(T) & 3][0];                        \
        bf16x8 bh0 = *(const bf16x8*)(bt_ + l * 8);                            \
        bf16x8 bh1 = *(const bf16x8*)(bt_ + 512 + l * 8);                      \
        bf16x8 bl0 = *(const bf16x8*)(bt_ + 1024 + l * 8);                     \
        bf16x8 bl1 = *(const bf16x8*)(bt_ + 1536 + l * 8);                     \
        const float cnv_ = cn_lds[(T) * 16 + col];                             \
        const f32x4 cA_ = {cnv_, cnv_, cnv_, cnv_};                            \
        const f32x4 z4_ = {0.f, 0.f, 0.f, 0.f};                                \
        const unsigned tt_ = (unsigned)(T);                                    \
        f32x4 a1_ = __builtin_amdgcn_mfma_f32_16x16x32_bf16(AH0, bh0, cA_, 0, 0, 0); \
        a1_ = __builtin_amdgcn_mfma_f32_16x16x32_bf16(AH1, bh1, a1_, 0, 0, 0); \
        a1_ = __builtin_amdgcn_mfma_f32_16x16x32_bf16(AL0, bh0, a1_, 0, 0, 0); \
        f32x4 a2_ = __builtin_amdgcn_mfma_f32_16x16x32_bf16(AH0, bl0, z4_, 0, 0, 0); \
        a2_ = __builtin_amdgcn_mfma_f32_16x16x32_bf16(AH1, bl1, a2_, 0, 0, 0); \
        a2_ = __builtin_amdgcn_mfma_f32_16x16x32_bf16(AL1, bh1, a2_, 0, 0, 0); \
        _Pragma("unroll")                                                      \
        for (int r = 0; r < 4; ++r) {                                          \
            float v_ = a1_[r] + a2_[r];                                        \
            unsigned pu_ = (__builtin_bit_cast(unsigned, v_) & 0xFFFFFFC0u) | tt_; \
            float f_ = __builtin_bit_cast(float, pu_);                         \
            b2[r] = __builtin_amdgcn_fmed3f(b1[r], f_, b2[r]);                 \
            b1[r] = fminf(b1[r], f_);                                          \
        }                                                                      \
    } while (0)

    for (int t = 0; t < 61; ++t) {
        WAITV(2);                         // own share of tile t arrived
        __builtin_amdgcn_s_barrier();     // all waves' shares arrived
        ISSUE(t + 3);                     // buf[(t-1)&3]: consumed last iter
        BODY(t);
    }
    WAITV(2); __builtin_amdgcn_s_barrier(); BODY(61);
    WAITV(1); __builtin_amdgcn_s_barrier(); BODY(62);
    WAITV(0); __builtin_amdgcn_s_barrier(); BODY(63);

    // ---- merge per-lane top-2 across the 16 code-lanes (packed values) ----
    {
        const int sk = 4 * (tx + (tx >> 4));   // skew: ~2-way banks
#pragma unroll
        for (int r = 0; r < 4; ++r) {
            mb1[sk + r] = b1[r];
            mb2[sk + r] = b2[r];
        }
    }
    __syncthreads();

    if (tx < 64) {   // thread tx owns local sample tx
        const int mw = tx >> 4;              // wave that held this sample
        const int mq = (tx >> 2) & 3;        // quad = (row within 16) >> 2
        const int mr = tx & 3;               // reg
        float B1 = 3.4e38f, B2 = 3.4e38f; int I1 = 0, I2 = 0;
#pragma unroll
        for (int c = 0; c < 16; ++c) {
            const int u = mw * 64 + mq * 16 + c;
            const int e = 4 * (u + (u >> 4)) + mr;
            float v1 = mb1[e];
            float v2 = mb2[e];
            int j1 = (int)(__builtin_bit_cast(unsigned, v1) & 63u) * 16 + c;
            int j2 = (int)(__builtin_bit_cast(unsigned, v2) & 63u) * 16 + c;
            if (v1 < B1)      { B2 = B1; I2 = I1; B1 = v1; I1 = j1; }
            else if (v1 < B2) { B2 = v1; I2 = j1; }
            if (v2 < B1)      { B2 = B1; I2 = I1; B1 = v2; I1 = j2; }
            else if (v2 < B2) { B2 = v2; I2 = j2; }
        }
        int winner = I1;
        if (B2 - B1 < MARGIN_KEY) {
            // exact fp32 rescore of both candidates (key = cn/2 - dot)
            const float* xp = xin + (size_t)(S0 + tx) * D;
            float a0 = 0, a1 = 0, a2 = 0, a3 = 0, e0 = 0, e1 = 0, e2 = 0, e3 = 0;
            for (int dd = 0; dd < D; dd += 4) {
                float x0 = xp[dd], x1 = xp[dd + 1], x2 = xp[dd + 2], x3 = xp[dd + 3];
                a0 = fmaf(x0, cm[(dd + 0) * K + I1], a0);
                a1 = fmaf(x1, cm[(dd + 1) * K + I1], a1);
                a2 = fmaf(x2, cm[(dd + 2) * K + I1], a2);
                a3 = fmaf(x3, cm[(dd + 3) * K + I1], a3);
                e0 = fmaf(x0, cm[(dd + 0) * K + I2], e0);
                e1 = fmaf(x1, cm[(dd + 1) * K + I2], e1);
                e2 = fmaf(x2, cm[(dd + 2) * K + I2], e2);
                e3 = fmaf(x3, cm[(dd + 3) * K + I2], e3);
            }
            float d1 = cn_lds[I1] - ((a0 + a1) + (a2 + a3));
            float d2 = cn_lds[I2] - ((e0 + e1) + (e2 + e3));
            if (d2 < d1 || (d2 == d1 && I2 < I1)) winner = I2;
        }
        widx[tx] = winner;
    }
    __syncthreads();

    // ---- gather (hi+lo reconstruct from packed P) + STE + loss partial ----
    float psum = 0.f;
    {
        const int sl = tx >> 2, d0 = (tx & 3) * 16;
        const int gs = S0 + sl;
        const int wi = widx[sl];
        const int gt = wi >> 4, gc = wi & 15;
        const int qq = (d0 >> 3) & 3;        // 0 or 2
        const int gf = d0 >> 5;              // 0 or 1
        const unsigned short* gh = P + ((size_t)((gt * 4 + gf) * 64) + qq * 16 + gc) * 8;
        const unsigned short* gl = P + ((size_t)((gt * 4 + 2 + gf) * 64) + qq * 16 + gc) * 8;
        bf16x8 h0 = *(const bf16x8*)(gh);          // dims d0..d0+8
        bf16x8 h1 = *(const bf16x8*)(gh + 128);    // dims d0+8..d0+16
        bf16x8 l0 = *(const bf16x8*)(gl);
        bf16x8 l1 = *(const bf16x8*)(gl + 128);
        const float* xr = xin + (size_t)gs * D + d0;
        float* oq = outq + (size_t)gs * D + d0;
#pragma unroll
        for (int g = 0; g < 4; ++g) {
            float4 xv = *(const float4*)(xr + 4 * g);
            float q0 = bf16f((unsigned short)(g < 2 ? h0[4 * g + 0] : h1[4 * g - 8 + 0])) +
                       bf16f((unsigned short)(g < 2 ? l0[4 * g + 0] : l1[4 * g - 8 + 0]));
            float q1 = bf16f((unsigned short)(g < 2 ? h0[4 * g + 1] : h1[4 * g - 8 + 1])) +
                       bf16f((unsigned short)(g < 2 ? l0[4 * g + 1] : l1[4 * g - 8 + 1]));
            float q2 = bf16f((unsigned short)(g < 2 ? h0[4 * g + 2] : h1[4 * g - 8 + 2])) +
                       bf16f((unsigned short)(g < 2 ? l0[4 * g + 2] : l1[4 * g - 8 + 2]));
            float q3 = bf16f((unsigned short)(g < 2 ? h0[4 * g + 3] : h1[4 * g - 8 + 3])) +
                       bf16f((unsigned short)(g < 2 ? l0[4 * g + 3] : l1[4 * g - 8 + 3]));
            float dx = q0 - xv.x, dy = q1 - xv.y, dz = q2 - xv.z, dw = q3 - xv.w;
            float4 o;
            o.x = xv.x + dx; o.y = xv.y + dy; o.z = xv.z + dz; o.w = xv.w + dw;
            *(float4*)(oq + 4 * g) = o;
            psum = fmaf(dx, dx, psum);
            psum = fmaf(dy, dy, psum);
            psum = fmaf(dz, dz, psum);
            psum = fmaf(dw, dw, psum);
        }
    }

    if (tx < 64)
        outidx[S0 + tx] = (float)widx[tx];

    __syncthreads();   // merge arrays dead; red aliases
    red[tx] = psum;
    __syncthreads();
    for (int st = 128; st > 0; st >>= 1) {
        if (tx < st) red[tx] += red[tx + st];
        __syncthreads();
    }
    if (tx == 0) {
        atomicAdd(acc_g, (double)red[0]);
        __threadfence();
        unsigned prev = atomicAdd(cnt_g, 1u);
        if (prev == gridDim.x - 1) {          // last block: fused finalize
            __threadfence();
            double a = atomicAdd(acc_g, 0.0); // device-scope read of total
            float m = (float)(a / (double)NEL);
            *loss_out = m + 0.25f * m;
        }
    }
#undef ISSUE
#undef WAITV
#undef BODY
}

extern "C" void kernel_launch(void* const* d_in, const int* in_sizes, int n_in,
                              void* d_out, int out_size, void* d_ws, size_t ws_size,
                              hipStream_t stream) {
    const float* xin = (const float*)d_in[0];   // [16,64,64,64] fp32
    const float* cm  = (const float*)d_in[1];   // [64,1024] fp32

    float* out     = (float*)d_out;
    float* outq    = out;                 // 4194304 floats
    float* outidx  = out + NEL;           // 65536 floats (indices)
    float* outloss = out + NEL + NS;      // 1 float

    // workspace: packed P 256 KB | cnorm 4 KB | acc 8 B | cnt 4 B
    unsigned short* P = (unsigned short*)d_ws;
    float*  cnorm = (float*)((char*)d_ws + 262144);
    double* acc   = (double*)((char*)d_ws + 266240);
    unsigned int* cnt = (unsigned int*)((char*)d_ws + 266248);

    vq_prep<<<64, 256, 0, stream>>>(cm, P, cnorm, acc, cnt);
    vq_main<<<1024, 256, 0, stream>>>(xin, cm, P, cnorm, outq, outidx,
                                      acc, cnt, outloss);
}